// Round 2
// baseline (3125.453 us; speedup 1.0000x reference)
//
#include <hip/hip_runtime.h>
#include <math.h>

#define TT 2048
#define DD 768
#define NN 256
#define NHH 12
#define BB 2

static inline int imin(int a, int b) { return a < b ? a : b; }

// ---------------------------------------------------------------------------
// K1: latent = x @ encoder[h]; x_sparse = relu; QR = rope(x_sparse).
// QR is stored into the out2 region of d_out (scratch until k4 overwrites it).
// M = B*T = 4096, K = 768, N = 256, per head h.
// ---------------------------------------------------------------------------
__global__ __launch_bounds__(256) void k1_encode(
    const float* __restrict__ x, const float* __restrict__ enc,
    float* __restrict__ qr) {
  const int h  = blockIdx.z;
  const int m0 = blockIdx.x * 64;
  const int n0 = blockIdx.y * 64;
  const int tid = threadIdx.x;
  const int tx = tid & 15, ty = tid >> 4;
  const int arow = tid >> 2, acol = (tid & 3) << 2;
  const int brow = tid >> 4, bcol = (tid & 15) << 2;
  __shared__ float As[16][68];   // k-major (transposed store)
  __shared__ float Bs[16][64];
  float acc[4][4] = {};
  const float* Ag = x + (size_t)(m0 + arow) * DD + acol;
  const float* Bg = enc + ((size_t)h * DD + brow) * NN + n0 + bcol;
  for (int k0 = 0; k0 < DD; k0 += 16) {
    float4 av = *(const float4*)(Ag + k0);
    float4 bv = *(const float4*)(Bg + (size_t)k0 * NN);
    As[acol + 0][arow] = av.x; As[acol + 1][arow] = av.y;
    As[acol + 2][arow] = av.z; As[acol + 3][arow] = av.w;
    *(float4*)&Bs[brow][bcol] = bv;
    __syncthreads();
#pragma unroll
    for (int k = 0; k < 16; ++k) {
      float a[4], b[4];
      *(float4*)a = *(const float4*)&As[k][ty << 2];
      *(float4*)b = *(const float4*)&Bs[k][tx << 2];
#pragma unroll
      for (int i = 0; i < 4; ++i)
#pragma unroll
        for (int j = 0; j < 4; ++j) acc[i][j] = fmaf(a[i], b[j], acc[i][j]);
    }
    __syncthreads();
  }
#pragma unroll
  for (int i = 0; i < 4; ++i) {
    const int m = m0 + (ty << 2) + i;
    const int b = m >> 11, t = m & (TT - 1);
    const float tf = (float)t;
    float* qrp = qr + ((size_t)(b * NHH + h) * TT + t) * NN + n0 + (tx << 2);
#pragma unroll
    for (int jp = 0; jp < 2; ++jp) {
      float v0 = fmaxf(acc[i][2 * jp], 0.f);
      float v1 = fmaxf(acc[i][2 * jp + 1], 0.f);
      const int q = n0 + (tx << 2) + 2 * jp;           // even: floor(n/2)*2
      // freq = 1/THETA^(q/N)/(2pi), THETA=2^16 -> 2^(-q/16) * 1/(2pi)
      float freq = exp2f((float)q * -0.0625f) * 0.15915494309189535f;
      float phase = tf * freq;
      float ph = (phase - floorf(phase)) * 6.283185307179586f;
      float s, c;
      sincosf(ph, &s, &c);
      qrp[2 * jp] = v0 * c - v1 * s;
      qrp[2 * jp + 1] = v1 * c + v0 * s;
    }
  }
}

// ---------------------------------------------------------------------------
// K2a: S[t,s] = QR[t,:]·QR[s,:] for s < t (strict lower). Per (b,h) slice.
// Only lower-triangular 64x64 tiles computed; diagonal tiles masked to zero.
// ---------------------------------------------------------------------------
__global__ __launch_bounds__(256) void k2a_scores(
    const float* __restrict__ qr, float* __restrict__ sc, int bh0) {
  const int t0 = blockIdx.y * 64;
  const int s0 = blockIdx.x * 64;
  if (s0 > t0) return;                       // strictly-upper tile: never read
  const int bh = bh0 + blockIdx.z;
  const float* q = qr + (size_t)bh * TT * NN;
  float* S = sc + (size_t)blockIdx.z * TT * TT;
  const int tid = threadIdx.x;
  const int tx = tid & 15, ty = tid >> 4;
  const int arow = tid >> 2, acol = (tid & 3) << 2;
  __shared__ float As[16][68];
  __shared__ float Bs[16][68];
  float acc[4][4] = {};
  const float* Ag = q + (size_t)(t0 + arow) * NN + acol;
  const float* Bg = q + (size_t)(s0 + arow) * NN + acol;
  for (int k0 = 0; k0 < NN; k0 += 16) {
    float4 av = *(const float4*)(Ag + k0);
    float4 bv = *(const float4*)(Bg + k0);
    As[acol + 0][arow] = av.x; As[acol + 1][arow] = av.y;
    As[acol + 2][arow] = av.z; As[acol + 3][arow] = av.w;
    Bs[acol + 0][arow] = bv.x; Bs[acol + 1][arow] = bv.y;
    Bs[acol + 2][arow] = bv.z; Bs[acol + 3][arow] = bv.w;
    __syncthreads();
#pragma unroll
    for (int k = 0; k < 16; ++k) {
      float a[4], b[4];
      *(float4*)a = *(const float4*)&As[k][ty << 2];
      *(float4*)b = *(const float4*)&Bs[k][tx << 2];
#pragma unroll
      for (int i = 0; i < 4; ++i)
#pragma unroll
        for (int j = 0; j < 4; ++j) acc[i][j] = fmaf(a[i], b[j], acc[i][j]);
    }
    __syncthreads();
  }
#pragma unroll
  for (int i = 0; i < 4; ++i) {
    const int t = t0 + (ty << 2) + i;
    float* row = S + (size_t)t * TT + s0 + (tx << 2);
#pragma unroll
    for (int j = 0; j < 4; ++j) {
      const int s = s0 + (tx << 2) + j;
      row[j] = (s < t) ? acc[i][j] : 0.f;
    }
  }
}

// ---------------------------------------------------------------------------
// K2b: yKV[t,d] = sum_{s<t} S[t,s] * x[b,s,d].  K-loop only runs to t0+64.
// yKV is a chunk-local buffer (slice index = blockIdx.z).
// ---------------------------------------------------------------------------
__global__ __launch_bounds__(256) void k2b_ykv(
    const float* __restrict__ sc, const float* __restrict__ x,
    float* __restrict__ ykv, int bh0) {
  const int bh = bh0 + blockIdx.z;
  const int b = bh / NHH;
  const int t0 = blockIdx.x * 64;
  const int d0 = blockIdx.y * 64;
  const float* S = sc + (size_t)blockIdx.z * TT * TT;
  const float* xb = x + (size_t)b * TT * DD;
  const int tid = threadIdx.x;
  const int tx = tid & 15, ty = tid >> 4;
  const int arow = tid >> 2, acol = (tid & 3) << 2;
  const int brow = tid >> 4, bcol = (tid & 15) << 2;
  __shared__ float As[16][68];
  __shared__ float Bs[16][64];
  float acc[4][4] = {};
  const float* Ag = S + (size_t)(t0 + arow) * TT + acol;
  const float* Bg = xb + (size_t)brow * DD + d0 + bcol;
  const int kmax = t0 + 64;
  for (int k0 = 0; k0 < kmax; k0 += 16) {
    float4 av = *(const float4*)(Ag + k0);
    float4 bv = *(const float4*)(Bg + (size_t)k0 * DD);
    As[acol + 0][arow] = av.x; As[acol + 1][arow] = av.y;
    As[acol + 2][arow] = av.z; As[acol + 3][arow] = av.w;
    *(float4*)&Bs[brow][bcol] = bv;
    __syncthreads();
#pragma unroll
    for (int k = 0; k < 16; ++k) {
      float a[4], b[4];
      *(float4*)a = *(const float4*)&As[k][ty << 2];
      *(float4*)b = *(const float4*)&Bs[k][tx << 2];
#pragma unroll
      for (int i = 0; i < 4; ++i)
#pragma unroll
        for (int j = 0; j < 4; ++j) acc[i][j] = fmaf(a[i], b[j], acc[i][j]);
    }
    __syncthreads();
  }
#pragma unroll
  for (int i = 0; i < 4; ++i) {
    const int t = t0 + (ty << 2) + i;
    float* o = ykv + ((size_t)blockIdx.z * TT + t) * DD + d0 + (tx << 2);
    *(float4*)o = make_float4(acc[i][0], acc[i][1], acc[i][2], acc[i][3]);
  }
}

// ---------------------------------------------------------------------------
// K3: per-row mean / rstd of chunk-local yKV (rows of length 768). 1 wave/row.
// ---------------------------------------------------------------------------
__global__ __launch_bounds__(256) void k3_stats(
    const float* __restrict__ ykv, float* __restrict__ mu, float* __restrict__ rs) {
  const int row = blockIdx.x * 4 + (threadIdx.x >> 6);
  const int lane = threadIdx.x & 63;
  const float* p = ykv + (size_t)row * DD;
  float sum = 0.f, sq = 0.f;
#pragma unroll
  for (int i = 0; i < 3; ++i) {
    float4 v = *(const float4*)&p[(lane << 2) + i * 256];
    sum += v.x + v.y + v.z + v.w;
    sq += v.x * v.x + v.y * v.y + v.z * v.z + v.w * v.w;
  }
#pragma unroll
  for (int off = 32; off; off >>= 1) {
    sum += __shfl_xor(sum, off);
    sq += __shfl_xor(sq, off);
  }
  if (lane == 0) {
    float m = sum * (1.f / 768.f);
    float v = sq * (1.f / 768.f) - m * m;
    mu[row] = m;
    rs[row] = rsqrtf(v + 1e-5f);
  }
}

// ---------------------------------------------------------------------------
// K4: y_sparse = relu(layernorm(yKV) @ encoder_v[h]).
// Reads QR from the out2 region, recovers x_sparse by inverse rotation,
// writes out2 = x_sparse * y_sparse in place.
// ---------------------------------------------------------------------------
__global__ __launch_bounds__(256) void k4_xy(
    const float* __restrict__ ykv, const float* __restrict__ mu,
    const float* __restrict__ rs, const float* __restrict__ encv,
    float* __restrict__ out2, int bh0) {
  const int z = blockIdx.z;
  const int bh = bh0 + z, h = bh % NHH;
  const int m0 = blockIdx.x * 64;
  const int n0 = blockIdx.y * 64;
  const int tid = threadIdx.x;
  const int tx = tid & 15, ty = tid >> 4;
  const int arow = tid >> 2, acol = (tid & 3) << 2;
  const int brow = tid >> 4, bcol = (tid & 15) << 2;
  __shared__ float As[16][68];
  __shared__ float Bs[16][64];
  float acc[4][4] = {};
  const int lrow = z * TT + m0 + arow;               // chunk-local row
  const float* Ag = ykv + (size_t)lrow * DD + acol;
  const float mrow = mu[lrow], rrow = rs[lrow];
  const float* Bg = encv + ((size_t)h * DD + brow) * NN + n0 + bcol;
  for (int k0 = 0; k0 < DD; k0 += 16) {
    float4 av = *(const float4*)(Ag + k0);
    float4 bv = *(const float4*)(Bg + (size_t)k0 * NN);
    As[acol + 0][arow] = (av.x - mrow) * rrow;
    As[acol + 1][arow] = (av.y - mrow) * rrow;
    As[acol + 2][arow] = (av.z - mrow) * rrow;
    As[acol + 3][arow] = (av.w - mrow) * rrow;
    *(float4*)&Bs[brow][bcol] = bv;
    __syncthreads();
#pragma unroll
    for (int k = 0; k < 16; ++k) {
      float a[4], b[4];
      *(float4*)a = *(const float4*)&As[k][ty << 2];
      *(float4*)b = *(const float4*)&Bs[k][tx << 2];
#pragma unroll
      for (int i = 0; i < 4; ++i)
#pragma unroll
        for (int j = 0; j < 4; ++j) acc[i][j] = fmaf(a[i], b[j], acc[i][j]);
    }
    __syncthreads();
  }
#pragma unroll
  for (int i = 0; i < 4; ++i) {
    const int t = m0 + (ty << 2) + i;
    float* o = out2 + ((size_t)bh * TT + t) * NN + n0 + (tx << 2);
    const float tf = (float)t;
    float qv[4];
    *(float4*)qv = *(const float4*)o;                // QR values
#pragma unroll
    for (int jp = 0; jp < 2; ++jp) {
      const int q = n0 + (tx << 2) + 2 * jp;
      float freq = exp2f((float)q * -0.0625f) * 0.15915494309189535f;
      float phase = tf * freq;
      float ph = (phase - floorf(phase)) * 6.283185307179586f;
      float s, c;
      sincosf(ph, &s, &c);
      // inverse rotation recovers x_sparse (orthogonal transform)
      float xs0 = qv[2 * jp] * c + qv[2 * jp + 1] * s;
      float xs1 = qv[2 * jp + 1] * c - qv[2 * jp] * s;
      o[2 * jp]     = fmaxf(acc[i][2 * jp], 0.f) * xs0;
      o[2 * jp + 1] = fmaxf(acc[i][2 * jp + 1], 0.f) * xs1;
    }
  }
}

// ---------------------------------------------------------------------------
// K5: yMLP = flat(xy_sparse) @ decoder.  M=4096, K=3072, N=768.
// flat[b,t,c] with c=h*256+n gathers from out2's (b,h,t,n) layout.
// ---------------------------------------------------------------------------
__global__ __launch_bounds__(256) void k5_mlp(
    const float* __restrict__ xy, const float* __restrict__ dec,
    float* __restrict__ ymlp) {
  const int m0 = blockIdx.x * 64;
  const int d0 = blockIdx.y * 64;
  const int tid = threadIdx.x;
  const int tx = tid & 15, ty = tid >> 4;
  const int arow = tid >> 2, acol = (tid & 3) << 2;
  const int brow = tid >> 4, bcol = (tid & 15) << 2;
  __shared__ float As[16][68];
  __shared__ float Bs[16][64];
  float acc[4][4] = {};
  const int m = m0 + arow;
  const int b = m >> 11, t = m & (TT - 1);
  for (int k0 = 0; k0 < NHH * NN; k0 += 16) {
    const int c = k0 + acol;
    const int h = c >> 8, n = c & 255;       // float4 stays within one h (16|256)
    float4 av = *(const float4*)&xy[((size_t)(b * NHH + h) * TT + t) * NN + n];
    float4 bv = *(const float4*)&dec[(size_t)(k0 + brow) * DD + d0 + bcol];
    As[acol + 0][arow] = av.x; As[acol + 1][arow] = av.y;
    As[acol + 2][arow] = av.z; As[acol + 3][arow] = av.w;
    *(float4*)&Bs[brow][bcol] = bv;
    __syncthreads();
#pragma unroll
    for (int k = 0; k < 16; ++k) {
      float a[4], bb[4];
      *(float4*)a = *(const float4*)&As[k][ty << 2];
      *(float4*)bb = *(const float4*)&Bs[k][tx << 2];
#pragma unroll
      for (int i = 0; i < 4; ++i)
#pragma unroll
        for (int j = 0; j < 4; ++j) acc[i][j] = fmaf(a[i], bb[j], acc[i][j]);
    }
    __syncthreads();
  }
#pragma unroll
  for (int i = 0; i < 4; ++i) {
    float* o = ymlp + (size_t)(m0 + (ty << 2) + i) * DD + d0 + (tx << 2);
    *(float4*)o = make_float4(acc[i][0], acc[i][1], acc[i][2], acc[i][3]);
  }
}

// ---------------------------------------------------------------------------
// K6: y = layernorm(yMLP) * sqrt(0.1/(ra+1e-6)) * scale; out1 = layernorm(x+y)
// One block per row (768 elements, 3 per thread).
// ---------------------------------------------------------------------------
__global__ __launch_bounds__(256) void k6_final(
    const float* __restrict__ ymlp, const float* __restrict__ x,
    const float* __restrict__ scale, const float* __restrict__ ra,
    float* __restrict__ out1) {
  const int row = blockIdx.x;
  const int tid = threadIdx.x;
  const int wid = tid >> 6, lane = tid & 63;
  __shared__ float red[8];
  float v[3];
  float sum = 0.f, sq = 0.f;
#pragma unroll
  for (int j = 0; j < 3; ++j) {
    v[j] = ymlp[(size_t)row * DD + tid + j * 256];
    sum += v[j]; sq += v[j] * v[j];
  }
#pragma unroll
  for (int off = 32; off; off >>= 1) { sum += __shfl_xor(sum, off); sq += __shfl_xor(sq, off); }
  if (lane == 0) { red[wid] = sum; red[4 + wid] = sq; }
  __syncthreads();
  sum = red[0] + red[1] + red[2] + red[3];
  sq = red[4] + red[5] + red[6] + red[7];
  const float m1 = sum * (1.f / 768.f);
  const float r1 = rsqrtf(sq * (1.f / 768.f) - m1 * m1 + 1e-5f);
  float z[3];
  float sum2 = 0.f, sq2 = 0.f;
#pragma unroll
  for (int j = 0; j < 3; ++j) {
    const int d = tid + j * 256;
    float y = (v[j] - m1) * r1 * sqrtf(0.1f / (ra[d] + 1e-6f)) * scale[d];
    z[j] = x[(size_t)row * DD + d] + y;
    sum2 += z[j]; sq2 += z[j] * z[j];
  }
  __syncthreads();
#pragma unroll
  for (int off = 32; off; off >>= 1) { sum2 += __shfl_xor(sum2, off); sq2 += __shfl_xor(sq2, off); }
  if (lane == 0) { red[wid] = sum2; red[4 + wid] = sq2; }
  __syncthreads();
  sum2 = red[0] + red[1] + red[2] + red[3];
  sq2 = red[4] + red[5] + red[6] + red[7];
  const float m2 = sum2 * (1.f / 768.f);
  const float r2 = rsqrtf(sq2 * (1.f / 768.f) - m2 * m2 + 1e-5f);
#pragma unroll
  for (int j = 0; j < 3; ++j)
    out1[(size_t)row * DD + tid + j * 256] = (z[j] - m2) * r2;
}

// ---------------------------------------------------------------------------
extern "C" void kernel_launch(void* const* d_in, const int* in_sizes, int n_in,
                              void* d_out, int out_size, void* d_ws, size_t ws_size,
                              hipStream_t stream) {
  const float* x = (const float*)d_in[0];
  const float* enc = (const float*)d_in[1];
  const float* encv = (const float*)d_in[2];
  const float* dec = (const float*)d_in[3];
  const float* scale = (const float*)d_in[4];
  const float* ra = (const float*)d_in[5];
  float* out1 = (float*)d_out;                       // (B,1,T,D)
  float* out2 = out1 + (size_t)BB * TT * DD;         // (B,NH,T,N); holds QR until k4

  // Workspace: per-(b,h)-slice cost = sc (TT*TT) + ykv (TT*DD) + mu/rs (2*TT).
  // ymlp (B*T*D = 3.15M floats) aliases the pool after the chunk loop.
  const size_t SLICE = (size_t)TT * TT + (size_t)TT * DD + 2 * (size_t)TT;  // 5.77M floats
  const size_t capf = ws_size / 4;
  int G = 1;
  {
    size_t g = capf / SLICE;
    if (g < 1) g = 1;
    if (g > (size_t)(BB * NHH)) g = BB * NHH;
    G = (int)g;
  }
  float* ws = (float*)d_ws;
  float* sc = ws;
  float* ykv = sc + (size_t)G * TT * TT;
  float* mu = ykv + (size_t)G * TT * DD;
  float* rsb = mu + (size_t)G * TT;
  float* ymlp = ws;                                   // reused after chunk loop

  k1_encode<<<dim3(64, 4, NHH), 256, 0, stream>>>(x, enc, out2);
  for (int bh0 = 0; bh0 < BB * NHH; bh0 += G) {
    const int g = imin(G, BB * NHH - bh0);
    k2a_scores<<<dim3(32, 32, g), 256, 0, stream>>>(out2, sc, bh0);
    k2b_ykv<<<dim3(32, 12, g), 256, 0, stream>>>(sc, x, ykv, bh0);
    k3_stats<<<dim3(g * TT / 4), 256, 0, stream>>>(ykv, mu, rsb);
    k4_xy<<<dim3(32, 4, g), 256, 0, stream>>>(ykv, mu, rsb, encv, out2, bh0);
  }
  k5_mlp<<<dim3(64, 12), 256, 0, stream>>>(out2, dec, ymlp);
  k6_final<<<dim3(BB * TT), 256, 0, stream>>>(ymlp, x, scale, ra, out1);
}

// Round 3
// 1084.967 us; speedup vs baseline: 2.8807x; 2.8807x over previous
//
#include <hip/hip_runtime.h>
#include <math.h>

#define TT 2048
#define DD 768
#define NN 256
#define NHH 12
#define BB 2

typedef unsigned short u16;
typedef __attribute__((ext_vector_type(8))) short bf16x8;
typedef __attribute__((ext_vector_type(4))) float f32x4;

static inline int imin(int a, int b) { return a < b ? a : b; }

__device__ __forceinline__ u16 f2b(float f) {
  union { float f; unsigned u; } a; a.f = f;
  unsigned r = a.u + 0x7FFF + ((a.u >> 16) & 1);
  return (u16)(r >> 16);
}
__device__ __forceinline__ float b2f(u16 h) {
  union { unsigned u; float f; } a; a.u = ((unsigned)h) << 16;
  return a.f;
}

__device__ __forceinline__ void async16(const void* g, void* l) {
  __builtin_amdgcn_global_load_lds(
      (const __attribute__((address_space(1))) unsigned*)g,
      (__attribute__((address_space(3))) unsigned*)l, 16, 0, 0);
}

// Stage a 128x32 bf16 tile (row-major, ld = global leading dim in elements)
// into LDS laid out [128][32] contiguous. gbase points at (tile_row0, k0).
__device__ __forceinline__ void stage128x32(
    const u16* __restrict__ gbase, size_t ld, u16* lds, int tid) {
  const int w = tid >> 6, l = tid & 63;
  const int r = l >> 2, kc = (l & 3) << 3;
#pragma unroll
  for (int q = 0; q < 2; ++q) {
    const int row0 = w * 32 + q * 16;
    async16(gbase + (size_t)(row0 + r) * ld + kc, lds + row0 * 32);
  }
}

// 16 MFMAs of one BK=32 step; wave (wr,wc) computes 64x64 of the 128x128 tile.
__device__ __forceinline__ void mfma_step(
    const u16* As, const u16* Bs, int wr, int wc, int lane, f32x4 acc[4][4]) {
  const int m16 = lane & 15, quad = lane >> 4;
  bf16x8 a[4], b[4];
#pragma unroll
  for (int i = 0; i < 4; ++i)
    a[i] = *(const bf16x8*)&As[(wr * 64 + i * 16 + m16) * 32 + quad * 8];
#pragma unroll
  for (int j = 0; j < 4; ++j)
    b[j] = *(const bf16x8*)&Bs[(wc * 64 + j * 16 + m16) * 32 + quad * 8];
#pragma unroll
  for (int i = 0; i < 4; ++i)
#pragma unroll
    for (int j = 0; j < 4; ++j)
      acc[i][j] = __builtin_amdgcn_mfma_f32_16x16x32_bf16(a[i], b[j], acc[i][j], 0, 0, 0);
}

#define GEMM_PROLOGUE()                                            \
  __shared__ __attribute__((aligned(16))) u16 As[128 * 32];        \
  __shared__ __attribute__((aligned(16))) u16 Bs[128 * 32];        \
  const int tid = threadIdx.x;                                     \
  const int w = tid >> 6, lane = tid & 63;                         \
  const int wr = w >> 1, wc = w & 1;                               \
  const int col16 = lane & 15, quad = lane >> 4;                   \
  f32x4 acc[4][4];                                                 \
  _Pragma("unroll") for (int i = 0; i < 4; ++i)                    \
  _Pragma("unroll") for (int j = 0; j < 4; ++j)                    \
      acc[i][j] = (f32x4){0.f, 0.f, 0.f, 0.f};

// ---------------------------------------------------------------------------
// cvt: fp32 -> bf16, same layout
// ---------------------------------------------------------------------------
__global__ __launch_bounds__(256) void cvt_bf16(
    const float* __restrict__ in, u16* __restrict__ out, size_t n4) {
  size_t i = ((size_t)blockIdx.x * 256 + threadIdx.x) * 4;
  if (i >= n4 * 4) return;
  float4 v = *(const float4*)&in[i];
  u16 o[4] = {f2b(v.x), f2b(v.y), f2b(v.z), f2b(v.w)};
  *(ushort4*)&out[i] = *(ushort4*)o;
}

// ---------------------------------------------------------------------------
// tcvt: fp32 (R x C) -> bf16 (C x R), batched by blockIdx.z with strides.
// ---------------------------------------------------------------------------
__global__ __launch_bounds__(256) void tcvt_bf16(
    const float* __restrict__ in, u16* __restrict__ out, int R, int C,
    size_t inStride, size_t outStride) {
  __shared__ float tile[32][33];
  const float* ip = in + (size_t)blockIdx.z * inStride;
  u16* op = out + (size_t)blockIdx.z * outStride;
  const int c0 = blockIdx.x * 32, r0 = blockIdx.y * 32;
  const int tx = threadIdx.x & 31, ty = threadIdx.x >> 5;
#pragma unroll
  for (int p = 0; p < 4; ++p)
    tile[ty + p * 8][tx] = ip[(size_t)(r0 + ty + p * 8) * C + c0 + tx];
  __syncthreads();
#pragma unroll
  for (int p = 0; p < 4; ++p)
    op[(size_t)(c0 + ty + p * 8) * R + r0 + tx] = f2b(tile[tx][ty + p * 8]);
}

// ---------------------------------------------------------------------------
// K1: latent = X16 @ ENCT[h]^T; relu; rope -> QR16 (bf16, [b][h][t][n]).
// M=4096, N=256, K=768 per head.
// ---------------------------------------------------------------------------
__global__ __launch_bounds__(256) void k1_encode(
    const u16* __restrict__ x16, const u16* __restrict__ enct,
    u16* __restrict__ qr16) {
  const int h = blockIdx.z;
  const int m0 = blockIdx.x * 128, n0 = blockIdx.y * 128;
  GEMM_PROLOGUE();
  for (int k0 = 0; k0 < DD; k0 += 32) {
    stage128x32(x16 + (size_t)m0 * DD + k0, DD, As, tid);
    stage128x32(enct + ((size_t)h * NN + n0) * DD + k0, DD, Bs, tid);
    __syncthreads();
    mfma_step(As, Bs, wr, wc, lane, acc);
    __syncthreads();
  }
#pragma unroll
  for (int i = 0; i < 4; ++i) {
#pragma unroll
    for (int j = 0; j < 4; ++j) {
      const int n = n0 + wc * 64 + j * 16 + col16;
      const int q = n & ~1;
      const float freq = exp2f((float)q * -0.0625f) * 0.15915494309189535f;
      float rv[4], pv[4];
#pragma unroll
      for (int r = 0; r < 4; ++r) rv[r] = fmaxf(acc[i][j][r], 0.f);
#pragma unroll
      for (int r = 0; r < 4; ++r) pv[r] = __shfl_xor(rv[r], 1);
#pragma unroll
      for (int r = 0; r < 4; ++r) {
        const int m = m0 + wr * 64 + i * 16 + quad * 4 + r;
        const int b = m >> 11, t = m & (TT - 1);
        float phase = (float)t * freq;
        float ph = (phase - floorf(phase)) * 6.283185307179586f;
        float s, c;
        sincosf(ph, &s, &c);
        float o = (n & 1) ? (rv[r] * c + pv[r] * s) : (rv[r] * c - pv[r] * s);
        qr16[((size_t)(b * NHH + h) * TT + t) * NN + n] = f2b(o);
      }
    }
  }
}

// ---------------------------------------------------------------------------
// K2a: S16 = QR16 @ QR16^T (strict lower; diag tiles masked). K=256.
// Triangular tile enumeration over 16x16 block-tiles (136 per slice).
// ---------------------------------------------------------------------------
__global__ __launch_bounds__(256) void k2a_scores(
    const u16* __restrict__ qr16, u16* __restrict__ s16, int bh0) {
  const int z = blockIdx.y;
  const int bh = bh0 + z;
  int bi = blockIdx.x;
  int ti = (int)((sqrtf(8.f * bi + 1.f) - 1.f) * 0.5f);
  while ((ti + 1) * (ti + 2) / 2 <= bi) ++ti;
  while (ti * (ti + 1) / 2 > bi) --ti;
  const int tj = bi - ti * (ti + 1) / 2;
  const int t0 = ti * 128, s0 = tj * 128;
  const u16* q = qr16 + (size_t)bh * TT * NN;
  u16* S = s16 + (size_t)z * TT * TT;
  GEMM_PROLOGUE();
  for (int k0 = 0; k0 < NN; k0 += 32) {
    stage128x32(q + (size_t)t0 * NN + k0, NN, As, tid);
    stage128x32(q + (size_t)s0 * NN + k0, NN, Bs, tid);
    __syncthreads();
    mfma_step(As, Bs, wr, wc, lane, acc);
    __syncthreads();
  }
  const bool diag = (ti == tj);
#pragma unroll
  for (int i = 0; i < 4; ++i)
#pragma unroll
    for (int j = 0; j < 4; ++j) {
      const int s = s0 + wc * 64 + j * 16 + col16;
#pragma unroll
      for (int r = 0; r < 4; ++r) {
        const int t = t0 + wr * 64 + i * 16 + quad * 4 + r;
        float v = acc[i][j][r];
        if (diag && s >= t) v = 0.f;
        S[(size_t)t * TT + s] = f2b(v);
      }
    }
}

// ---------------------------------------------------------------------------
// K2b: ykv(fp32) = S16 @ XT16[b]^T.  M=2048, N=768, K=t0+128 (causal band).
// ---------------------------------------------------------------------------
__global__ __launch_bounds__(256) void k2b_ykv(
    const u16* __restrict__ s16, const u16* __restrict__ xt16,
    float* __restrict__ ykv, int bh0) {
  const int z = blockIdx.z;
  const int bh = bh0 + z, b = bh / NHH;
  const int t0 = blockIdx.x * 128, d0 = blockIdx.y * 128;
  const u16* S = s16 + (size_t)z * TT * TT;
  const u16* X = xt16 + (size_t)b * DD * TT;
  GEMM_PROLOGUE();
  const int kmax = t0 + 128;
  for (int k0 = 0; k0 < kmax; k0 += 32) {
    stage128x32(S + (size_t)t0 * TT + k0, TT, As, tid);
    stage128x32(X + (size_t)d0 * TT + k0, TT, Bs, tid);
    __syncthreads();
    mfma_step(As, Bs, wr, wc, lane, acc);
    __syncthreads();
  }
#pragma unroll
  for (int i = 0; i < 4; ++i)
#pragma unroll
    for (int j = 0; j < 4; ++j) {
      const int d = d0 + wc * 64 + j * 16 + col16;
#pragma unroll
      for (int r = 0; r < 4; ++r) {
        const int t = t0 + wr * 64 + i * 16 + quad * 4 + r;
        ykv[((size_t)z * TT + t) * DD + d] = acc[i][j][r];
      }
    }
}

// ---------------------------------------------------------------------------
// K3: per-row layernorm of ykv -> ykv16 (bf16). One wave per row of 768.
// ---------------------------------------------------------------------------
__global__ __launch_bounds__(256) void k3_norm(
    const float* __restrict__ ykv, u16* __restrict__ ykv16) {
  const int row = blockIdx.x * 4 + (threadIdx.x >> 6);
  const int lane = threadIdx.x & 63;
  const float* p = ykv + (size_t)row * DD;
  float4 v[3];
  float sum = 0.f, sq = 0.f;
#pragma unroll
  for (int i = 0; i < 3; ++i) {
    v[i] = *(const float4*)&p[(lane << 2) + i * 256];
    sum += v[i].x + v[i].y + v[i].z + v[i].w;
    sq += v[i].x * v[i].x + v[i].y * v[i].y + v[i].z * v[i].z + v[i].w * v[i].w;
  }
#pragma unroll
  for (int off = 32; off; off >>= 1) {
    sum += __shfl_xor(sum, off);
    sq += __shfl_xor(sq, off);
  }
  const float m = sum * (1.f / 768.f);
  const float r = rsqrtf(sq * (1.f / 768.f) - m * m + 1e-5f);
  u16* o = ykv16 + (size_t)row * DD;
#pragma unroll
  for (int i = 0; i < 3; ++i) {
    u16 ov[4] = {f2b((v[i].x - m) * r), f2b((v[i].y - m) * r),
                 f2b((v[i].z - m) * r), f2b((v[i].w - m) * r)};
    *(ushort4*)&o[(lane << 2) + i * 256] = *(ushort4*)ov;
  }
}

// ---------------------------------------------------------------------------
// K4: y_sparse = relu(ykv16 @ ENCVT[h]^T); xs via inverse rope of QR16;
// out2 = xs*ys (fp32) and XY16 (bf16).  M=2048, N=256, K=768.
// ---------------------------------------------------------------------------
__global__ __launch_bounds__(256) void k4_xy(
    const u16* __restrict__ ykv16, const u16* __restrict__ encvt,
    const u16* __restrict__ qr16, float* __restrict__ out2,
    u16* __restrict__ xy16, int bh0) {
  const int z = blockIdx.z;
  const int bh = bh0 + z, h = bh % NHH;
  const int t0 = blockIdx.x * 128, n0 = blockIdx.y * 128;
  GEMM_PROLOGUE();
  for (int k0 = 0; k0 < DD; k0 += 32) {
    stage128x32(ykv16 + ((size_t)z * TT + t0) * DD + k0, DD, As, tid);
    stage128x32(encvt + ((size_t)h * NN + n0) * DD + k0, DD, Bs, tid);
    __syncthreads();
    mfma_step(As, Bs, wr, wc, lane, acc);
    __syncthreads();
  }
#pragma unroll
  for (int i = 0; i < 4; ++i)
#pragma unroll
    for (int j = 0; j < 4; ++j) {
      const int n = n0 + wc * 64 + j * 16 + col16;
      const int qn = n & ~1;
      const float freq = exp2f((float)qn * -0.0625f) * 0.15915494309189535f;
#pragma unroll
      for (int r = 0; r < 4; ++r) {
        const int t = t0 + wr * 64 + i * 16 + quad * 4 + r;
        const size_t gi = ((size_t)bh * TT + t) * NN + n;
        float ys = fmaxf(acc[i][j][r], 0.f);
        float qs = b2f(qr16[gi]);
        float qp = b2f(qr16[gi ^ 1]);
        float phase = (float)t * freq;
        float ph = (phase - floorf(phase)) * 6.283185307179586f;
        float s, c;
        sincosf(ph, &s, &c);
        float xs = (n & 1) ? (qs * c - qp * s) : (qs * c + qp * s);
        float val = ys * xs;
        out2[gi] = val;
        xy16[gi] = f2b(val);
      }
    }
}

// ---------------------------------------------------------------------------
// K5: ymlp = flat(XY16) @ DECT^T.  M=4096, N=768, K=3072.
// A row m=(b,t), k=h*256+n gathered from XY16's (b,h,t,n) layout.
// ---------------------------------------------------------------------------
__global__ __launch_bounds__(256) void k5_mlp(
    const u16* __restrict__ xy16, const u16* __restrict__ dect,
    float* __restrict__ ymlp) {
  const int m0 = blockIdx.x * 128, d0 = blockIdx.y * 128;
  GEMM_PROLOGUE();
  for (int k0 = 0; k0 < NHH * NN; k0 += 32) {
    {  // gather-stage A
      const int l = tid & 63;
      const int hh = k0 >> 8, kk = (k0 & 255) + ((l & 3) << 3);
#pragma unroll
      for (int q = 0; q < 2; ++q) {
        const int row0 = w * 32 + q * 16;
        const int m = m0 + row0 + (l >> 2);
        const int b = m >> 11, t = m & (TT - 1);
        async16(xy16 + ((size_t)(b * NHH + hh) * TT + t) * NN + kk,
                As + row0 * 32);
      }
    }
    stage128x32(dect + (size_t)d0 * (NHH * NN) + k0, NHH * NN, Bs, tid);
    __syncthreads();
    mfma_step(As, Bs, wr, wc, lane, acc);
    __syncthreads();
  }
#pragma unroll
  for (int i = 0; i < 4; ++i)
#pragma unroll
    for (int j = 0; j < 4; ++j) {
      const int d = d0 + wc * 64 + j * 16 + col16;
#pragma unroll
      for (int r = 0; r < 4; ++r) {
        const int m = m0 + wr * 64 + i * 16 + quad * 4 + r;
        ymlp[(size_t)m * DD + d] = acc[i][j][r];
      }
    }
}

// ---------------------------------------------------------------------------
// K6: y = ln(ymlp)*sqrt(0.1/(ra+1e-6))*scale; out1 = ln(x+y). Block per row.
// ---------------------------------------------------------------------------
__global__ __launch_bounds__(256) void k6_final(
    const float* __restrict__ ymlp, const float* __restrict__ x,
    const float* __restrict__ scale, const float* __restrict__ ra,
    float* __restrict__ out1) {
  const int row = blockIdx.x;
  const int tid = threadIdx.x;
  const int wid = tid >> 6, lane = tid & 63;
  __shared__ float red[8];
  float v[3];
  float sum = 0.f, sq = 0.f;
#pragma unroll
  for (int j = 0; j < 3; ++j) {
    v[j] = ymlp[(size_t)row * DD + tid + j * 256];
    sum += v[j]; sq += v[j] * v[j];
  }
#pragma unroll
  for (int off = 32; off; off >>= 1) { sum += __shfl_xor(sum, off); sq += __shfl_xor(sq, off); }
  if (lane == 0) { red[wid] = sum; red[4 + wid] = sq; }
  __syncthreads();
  sum = red[0] + red[1] + red[2] + red[3];
  sq = red[4] + red[5] + red[6] + red[7];
  const float m1 = sum * (1.f / 768.f);
  const float r1 = rsqrtf(sq * (1.f / 768.f) - m1 * m1 + 1e-5f);
  float z[3];
  float sum2 = 0.f, sq2 = 0.f;
#pragma unroll
  for (int j = 0; j < 3; ++j) {
    const int d = tid + j * 256;
    float y = (v[j] - m1) * r1 * sqrtf(0.1f / (ra[d] + 1e-6f)) * scale[d];
    z[j] = x[(size_t)row * DD + d] + y;
    sum2 += z[j]; sq2 += z[j] * z[j];
  }
  __syncthreads();
#pragma unroll
  for (int off = 32; off; off >>= 1) { sum2 += __shfl_xor(sum2, off); sq2 += __shfl_xor(sq2, off); }
  if (lane == 0) { red[wid] = sum2; red[4 + wid] = sq2; }
  __syncthreads();
  sum2 = red[0] + red[1] + red[2] + red[3];
  sq2 = red[4] + red[5] + red[6] + red[7];
  const float m2 = sum2 * (1.f / 768.f);
  const float r2 = rsqrtf(sq2 * (1.f / 768.f) - m2 * m2 + 1e-5f);
#pragma unroll
  for (int j = 0; j < 3; ++j)
    out1[(size_t)row * DD + tid + j * 256] = (z[j] - m2) * r2;
}

// ---------------------------------------------------------------------------
extern "C" void kernel_launch(void* const* d_in, const int* in_sizes, int n_in,
                              void* d_out, int out_size, void* d_ws, size_t ws_size,
                              hipStream_t stream) {
  const float* x = (const float*)d_in[0];
  const float* enc = (const float*)d_in[1];
  const float* encv = (const float*)d_in[2];
  const float* dec = (const float*)d_in[3];
  const float* scale = (const float*)d_in[4];
  const float* ra = (const float*)d_in[5];
  float* out1 = (float*)d_out;
  float* out2 = out1 + (size_t)BB * TT * DD;

  // Fixed bf16 buffers in ws (all sizes multiples of 16 B):
  unsigned char* p = (unsigned char*)d_ws;
  u16* X16 = (u16*)p;   p += (size_t)BB * TT * DD * 2;        // [m][d]
  u16* XT16 = (u16*)p;  p += (size_t)BB * DD * TT * 2;        // [b][d][t]
  u16* ENCT = (u16*)p;  p += (size_t)NHH * NN * DD * 2;       // [h][n][d]
  u16* ENCVT = (u16*)p; p += (size_t)NHH * NN * DD * 2;       // [h][n][d]
  u16* DECT = (u16*)p;  p += (size_t)DD * NHH * NN * 2;       // [d][c]
  u16* QR16 = (u16*)p;  p += (size_t)BB * NHH * TT * NN * 2;  // [b][h][t][n]
  u16* XY16 = (u16*)p;  p += (size_t)BB * NHH * TT * NN * 2;  // [b][h][t][n]
  // Per-slice pool: S16 + ykv(fp32) + ykv16
  const size_t SLICE_B = (size_t)TT * TT * 2 + (size_t)TT * DD * 4 + (size_t)TT * DD * 2;
  size_t rem = ws_size - (size_t)(p - (unsigned char*)d_ws);
  int G = (int)(rem / SLICE_B);
  if (G < 1) G = 1;
  if (G > BB * NHH) G = BB * NHH;
  u16* S16 = (u16*)p;
  float* ykv = (float*)(p + (size_t)G * TT * TT * 2);
  u16* ykv16 = (u16*)((unsigned char*)ykv + (size_t)G * TT * DD * 4);
  float* ymlp = (float*)p;  // aliases slice pool after the chunk loop

  // One-time conversions / transposes
  cvt_bf16<<<dim3((BB * TT * DD) / 1024), 256, 0, stream>>>(x, X16, (size_t)BB * TT * DD / 4);
  tcvt_bf16<<<dim3(DD / 32, TT / 32, BB), 256, 0, stream>>>(
      x, XT16, TT, DD, (size_t)TT * DD, (size_t)DD * TT);
  tcvt_bf16<<<dim3(NN / 32, DD / 32, NHH), 256, 0, stream>>>(
      enc, ENCT, DD, NN, (size_t)DD * NN, (size_t)NN * DD);
  tcvt_bf16<<<dim3(NN / 32, DD / 32, NHH), 256, 0, stream>>>(
      encv, ENCVT, DD, NN, (size_t)DD * NN, (size_t)NN * DD);
  tcvt_bf16<<<dim3(DD / 32, (NHH * NN) / 32, 1), 256, 0, stream>>>(
      dec, DECT, NHH * NN, DD, 0, 0);

  k1_encode<<<dim3(BB * TT / 128, NN / 128, NHH), 256, 0, stream>>>(X16, ENCT, QR16);

  for (int bh0 = 0; bh0 < BB * NHH; bh0 += G) {
    const int g = imin(G, BB * NHH - bh0);
    k2a_scores<<<dim3(136, g), 256, 0, stream>>>(QR16, S16, bh0);
    k2b_ykv<<<dim3(TT / 128, DD / 128, g), 256, 0, stream>>>(S16, XT16, ykv, bh0);
    k3_norm<<<dim3(g * TT / 4), 256, 0, stream>>>(ykv, ykv16);
    k4_xy<<<dim3(TT / 128, NN / 128, g), 256, 0, stream>>>(
        ykv16, ENCVT, QR16, out2, XY16, bh0);
  }
  k5_mlp<<<dim3(BB * TT / 128, DD / 128), 256, 0, stream>>>(XY16, DECT, ymlp);
  k6_final<<<dim3(BB * TT), 256, 0, stream>>>(ymlp, x, scale, ra, out1);
}

// Round 4
// 606.569 us; speedup vs baseline: 5.1527x; 1.7887x over previous
//
#include <hip/hip_runtime.h>
#include <math.h>

#define TT 2048
#define DD 768
#define NN 256
#define NHH 12
#define BB 2

typedef unsigned short u16;
typedef __attribute__((ext_vector_type(8))) short bf16x8;
typedef __attribute__((ext_vector_type(8))) unsigned short u16x8;
typedef __attribute__((ext_vector_type(4))) float f32x4;

static inline int imin(int a, int b) { return a < b ? a : b; }

__device__ __forceinline__ u16 f2b(float f) {
  union { float f; unsigned u; } a; a.f = f;
  unsigned r = a.u + 0x7FFF + ((a.u >> 16) & 1);
  return (u16)(r >> 16);
}
__device__ __forceinline__ float b2f(u16 h) {
  union { unsigned u; float f; } a; a.u = ((unsigned)h) << 16;
  return a.f;
}

__device__ __forceinline__ void async16(const void* g, void* l) {
  __builtin_amdgcn_global_load_lds(
      (const __attribute__((address_space(1))) unsigned*)g,
      (__attribute__((address_space(3))) unsigned*)l, 16, 0, 0);
}

// Stage a 128x32 bf16 tile (row-major, ld = global leading dim in elements)
// into LDS laid out [128][32] contiguous. gbase points at (tile_row0, k0).
__device__ __forceinline__ void stage128x32(
    const u16* __restrict__ gbase, size_t ld, u16* lds, int tid) {
  const int w = tid >> 6, l = tid & 63;
  const int r = l >> 2, kc = (l & 3) << 3;
#pragma unroll
  for (int q = 0; q < 2; ++q) {
    const int row0 = w * 32 + q * 16;
    async16(gbase + (size_t)(row0 + r) * ld + kc, lds + row0 * 32);
  }
}

// 16 MFMAs of one BK=32 step; wave (wr,wc) computes 64x64 of the 128x128 tile.
__device__ __forceinline__ void mfma_step(
    const u16* As, const u16* Bs, int wr, int wc, int lane, f32x4 acc[4][4]) {
  const int m16 = lane & 15, quad = lane >> 4;
  bf16x8 a[4], b[4];
#pragma unroll
  for (int i = 0; i < 4; ++i)
    a[i] = *(const bf16x8*)&As[(wr * 64 + i * 16 + m16) * 32 + quad * 8];
#pragma unroll
  for (int j = 0; j < 4; ++j)
    b[j] = *(const bf16x8*)&Bs[(wc * 64 + j * 16 + m16) * 32 + quad * 8];
#pragma unroll
  for (int i = 0; i < 4; ++i)
#pragma unroll
    for (int j = 0; j < 4; ++j)
      acc[i][j] = __builtin_amdgcn_mfma_f32_16x16x32_bf16(a[i], b[j], acc[i][j], 0, 0, 0);
}

// copy a 64x128 u16 tile from LDS (row-major, no pad) to global rows of ld.
__device__ __forceinline__ void copy_out64(
    const u16* buf, u16* g, size_t ld, int tid) {
#pragma unroll
  for (int s = 0; s < 4; ++s) {
    const int off = (s * 256 + tid) * 8;
    const int row = off >> 7, col = off & 127;
    *(u16x8*)&g[(size_t)row * ld + col] = *(const u16x8*)&buf[off];
  }
}

#define GEMM_PROLOGUE()                                            \
  __shared__ __attribute__((aligned(16))) u16 smem[8192];          \
  u16* As = smem;                                                  \
  u16* Bs = smem + 4096;                                           \
  const int tid = threadIdx.x;                                     \
  const int w = tid >> 6, lane = tid & 63;                         \
  const int wr = w >> 1, wc = w & 1;                               \
  const int col16 = lane & 15, quad = lane >> 4;                   \
  f32x4 acc[4][4];                                                 \
  _Pragma("unroll") for (int i = 0; i < 4; ++i)                    \
  _Pragma("unroll") for (int j = 0; j < 4; ++j)                    \
      acc[i][j] = (f32x4){0.f, 0.f, 0.f, 0.f};

// ---------------------------------------------------------------------------
// cvt: fp32 -> bf16, same layout
// ---------------------------------------------------------------------------
__global__ __launch_bounds__(256) void cvt_bf16(
    const float* __restrict__ in, u16* __restrict__ out, size_t n4) {
  size_t i = ((size_t)blockIdx.x * 256 + threadIdx.x) * 4;
  if (i >= n4 * 4) return;
  float4 v = *(const float4*)&in[i];
  u16 o[4] = {f2b(v.x), f2b(v.y), f2b(v.z), f2b(v.w)};
  *(ushort4*)&out[i] = *(ushort4*)o;
}

// ---------------------------------------------------------------------------
// tcvt: fp32 (R x C) -> bf16 (C x R), batched by blockIdx.z with strides.
// ---------------------------------------------------------------------------
__global__ __launch_bounds__(256) void tcvt_bf16(
    const float* __restrict__ in, u16* __restrict__ out, int R, int C,
    size_t inStride, size_t outStride) {
  __shared__ float tile[32][33];
  const float* ip = in + (size_t)blockIdx.z * inStride;
  u16* op = out + (size_t)blockIdx.z * outStride;
  const int c0 = blockIdx.x * 32, r0 = blockIdx.y * 32;
  const int tx = threadIdx.x & 31, ty = threadIdx.x >> 5;
#pragma unroll
  for (int p = 0; p < 4; ++p)
    tile[ty + p * 8][tx] = ip[(size_t)(r0 + ty + p * 8) * C + c0 + tx];
  __syncthreads();
#pragma unroll
  for (int p = 0; p < 4; ++p)
    op[(size_t)(c0 + ty + p * 8) * R + r0 + tx] = f2b(tile[tx][ty + p * 8]);
}

// ---------------------------------------------------------------------------
// colsum[h*NN+n] = sum_d ENCVT[h][n][d]  (for the k4 layernorm-affine trick)
// ---------------------------------------------------------------------------
__global__ __launch_bounds__(256) void k_colsum(
    const u16* __restrict__ encvt, float* __restrict__ colsum) {
  const int row = blockIdx.x * 4 + (threadIdx.x >> 6);
  const int lane = threadIdx.x & 63;
  const u16* pr = encvt + (size_t)row * DD;
  float s = 0.f;
#pragma unroll
  for (int i = 0; i < 3; ++i) {
    ushort4 v = *(const ushort4*)&pr[(lane << 2) + i * 256];
    s += b2f(v.x) + b2f(v.y) + b2f(v.z) + b2f(v.w);
  }
#pragma unroll
  for (int off = 32; off; off >>= 1) s += __shfl_xor(s, off);
  if (lane == 0) colsum[row] = s;
}

// ---------------------------------------------------------------------------
// K1: latent = X16 @ ENCT[h]^T; relu; rope -> QR16 (bf16, [b][h][t][n]).
// M=4096, N=256, K=768 per head. Coalesced store via LDS restage.
// ---------------------------------------------------------------------------
__global__ __launch_bounds__(256) void k1_encode(
    const u16* __restrict__ x16, const u16* __restrict__ enct,
    u16* __restrict__ qr16) {
  const int h = blockIdx.z;
  const int m0 = blockIdx.x * 128, n0 = blockIdx.y * 128;
  GEMM_PROLOGUE();
  for (int k0 = 0; k0 < DD; k0 += 32) {
    stage128x32(x16 + (size_t)m0 * DD + k0, DD, As, tid);
    stage128x32(enct + ((size_t)h * NN + n0) * DD + k0, DD, Bs, tid);
    __syncthreads();
    mfma_step(As, Bs, wr, wc, lane, acc);
    __syncthreads();
  }
#pragma unroll
  for (int p = 0; p < 2; ++p) {
    __syncthreads();
    if (wr == p) {
#pragma unroll
      for (int i = 0; i < 4; ++i)
#pragma unroll
        for (int j = 0; j < 4; ++j) {
          const int n = n0 + wc * 64 + j * 16 + col16;
          const int q = n & ~1;
          const float freq = exp2f((float)q * -0.0625f) * 0.15915494309189535f;
          float rv[4], pv[4];
#pragma unroll
          for (int r = 0; r < 4; ++r) rv[r] = fmaxf(acc[i][j][r], 0.f);
#pragma unroll
          for (int r = 0; r < 4; ++r) pv[r] = __shfl_xor(rv[r], 1);
#pragma unroll
          for (int r = 0; r < 4; ++r) {
            const int lr = i * 16 + quad * 4 + r;
            const int t = (m0 + p * 64 + lr) & (TT - 1);
            float phase = (float)t * freq;
            float ph = (phase - floorf(phase)) * 6.283185307179586f;
            float s = __sinf(ph), c = __cosf(ph);
            float o = (n & 1) ? (rv[r] * c + pv[r] * s) : (rv[r] * c - pv[r] * s);
            smem[lr * 128 + wc * 64 + j * 16 + col16] = f2b(o);
          }
        }
    }
    __syncthreads();
    const int m = m0 + p * 64;
    const int b = m >> 11, t = m & (TT - 1);
    copy_out64(smem, qr16 + ((size_t)(b * NHH + h) * TT + t) * NN + n0, NN, tid);
  }
}

// ---------------------------------------------------------------------------
// K2a: S16 = QR16 @ QR16^T (strict lower; diag tiles masked). K=256.
// Triangular tile enumeration (136 tiles / slice). Coalesced LDS store.
// ---------------------------------------------------------------------------
__global__ __launch_bounds__(256) void k2a_scores(
    const u16* __restrict__ qr16, u16* __restrict__ s16, int bh0) {
  const int z = blockIdx.y;
  const int bh = bh0 + z;
  int bi = blockIdx.x;
  int ti = (int)((sqrtf(8.f * bi + 1.f) - 1.f) * 0.5f);
  while ((ti + 1) * (ti + 2) / 2 <= bi) ++ti;
  while (ti * (ti + 1) / 2 > bi) --ti;
  const int tj = bi - ti * (ti + 1) / 2;
  const int t0 = ti * 128, s0 = tj * 128;
  const u16* q = qr16 + (size_t)bh * TT * NN;
  u16* S = s16 + (size_t)z * TT * TT;
  GEMM_PROLOGUE();
  for (int k0 = 0; k0 < NN; k0 += 32) {
    stage128x32(q + (size_t)t0 * NN + k0, NN, As, tid);
    stage128x32(q + (size_t)s0 * NN + k0, NN, Bs, tid);
    __syncthreads();
    mfma_step(As, Bs, wr, wc, lane, acc);
    __syncthreads();
  }
  const bool diag = (ti == tj);
#pragma unroll
  for (int p = 0; p < 2; ++p) {
    __syncthreads();
    if (wr == p) {
#pragma unroll
      for (int i = 0; i < 4; ++i)
#pragma unroll
        for (int j = 0; j < 4; ++j) {
          const int s = s0 + wc * 64 + j * 16 + col16;
#pragma unroll
          for (int r = 0; r < 4; ++r) {
            const int lr = i * 16 + quad * 4 + r;
            const int t = t0 + p * 64 + lr;
            float v = acc[i][j][r];
            if (diag && s >= t) v = 0.f;
            smem[lr * 128 + wc * 64 + j * 16 + col16] = f2b(v);
          }
        }
    }
    __syncthreads();
    copy_out64(smem, S + (size_t)(t0 + p * 64) * TT + s0, TT, tid);
  }
}

// ---------------------------------------------------------------------------
// K2b: ykv16(bf16) = S16 @ XT16[b]^T.  M=2048, N=768, K=t0+128 (causal band).
// Grid: x = d-tile (fast), y = t-tile (slow) for S-band L2 reuse.
// ---------------------------------------------------------------------------
__global__ __launch_bounds__(256) void k2b_ykv(
    const u16* __restrict__ s16, const u16* __restrict__ xt16,
    u16* __restrict__ ykv16, int bh0) {
  const int z = blockIdx.z;
  const int bh = bh0 + z, b = bh / NHH;
  const int t0 = blockIdx.y * 128, d0 = blockIdx.x * 128;
  const u16* S = s16 + (size_t)z * TT * TT;
  const u16* X = xt16 + (size_t)b * DD * TT;
  GEMM_PROLOGUE();
  const int kmax = t0 + 128;
  for (int k0 = 0; k0 < kmax; k0 += 32) {
    stage128x32(S + (size_t)t0 * TT + k0, TT, As, tid);
    stage128x32(X + (size_t)d0 * TT + k0, TT, Bs, tid);
    __syncthreads();
    mfma_step(As, Bs, wr, wc, lane, acc);
    __syncthreads();
  }
#pragma unroll
  for (int p = 0; p < 2; ++p) {
    __syncthreads();
    if (wr == p) {
#pragma unroll
      for (int i = 0; i < 4; ++i)
#pragma unroll
        for (int j = 0; j < 4; ++j)
#pragma unroll
          for (int r = 0; r < 4; ++r) {
            const int lr = i * 16 + quad * 4 + r;
            smem[lr * 128 + wc * 64 + j * 16 + col16] = f2b(acc[i][j][r]);
          }
    }
    __syncthreads();
    copy_out64(smem, ykv16 + ((size_t)z * TT + t0 + p * 64) * DD + d0, DD, tid);
  }
}

// ---------------------------------------------------------------------------
// K3: per-row mean/rstd of ykv16 (bf16 rows of 768). One wave per row.
// ---------------------------------------------------------------------------
__global__ __launch_bounds__(256) void k3_stats(
    const u16* __restrict__ ykv16, float* __restrict__ mu, float* __restrict__ rs) {
  const int row = blockIdx.x * 4 + (threadIdx.x >> 6);
  const int lane = threadIdx.x & 63;
  const u16* p = ykv16 + (size_t)row * DD;
  float sum = 0.f, sq = 0.f;
#pragma unroll
  for (int i = 0; i < 3; ++i) {
    ushort4 v = *(const ushort4*)&p[(lane << 2) + i * 256];
    float f0 = b2f(v.x), f1 = b2f(v.y), f2 = b2f(v.z), f3 = b2f(v.w);
    sum += f0 + f1 + f2 + f3;
    sq += f0 * f0 + f1 * f1 + f2 * f2 + f3 * f3;
  }
#pragma unroll
  for (int off = 32; off; off >>= 1) {
    sum += __shfl_xor(sum, off);
    sq += __shfl_xor(sq, off);
  }
  if (lane == 0) {
    float m = sum * (1.f / 768.f);
    float v = sq * (1.f / 768.f) - m * m;
    mu[row] = m;
    rs[row] = rsqrtf(v + 1e-5f);
  }
}

// ---------------------------------------------------------------------------
// K4: raw GEMM ykv16 @ ENCVT[h]^T with LN applied as epilogue affine:
//   normed = rs*acc - rs*mu*colsum[h][n];  ys = relu(normed);
//   xs via inverse rope of QR16;  out2 = xs*ys (fp32) + XY16 (bf16).
// ---------------------------------------------------------------------------
__global__ __launch_bounds__(256) void k4_xy(
    const u16* __restrict__ ykv16, const u16* __restrict__ encvt,
    const u16* __restrict__ qr16, const float* __restrict__ mu,
    const float* __restrict__ rs, const float* __restrict__ colsum,
    float* __restrict__ out2, u16* __restrict__ xy16, int bh0) {
  const int z = blockIdx.z;
  const int bh = bh0 + z, h = bh % NHH;
  const int t0 = blockIdx.x * 128, n0 = blockIdx.y * 128;
  GEMM_PROLOGUE();
  for (int k0 = 0; k0 < DD; k0 += 32) {
    stage128x32(ykv16 + ((size_t)z * TT + t0) * DD + k0, DD, As, tid);
    stage128x32(encvt + ((size_t)h * NN + n0) * DD + k0, DD, Bs, tid);
    __syncthreads();
    mfma_step(As, Bs, wr, wc, lane, acc);
    __syncthreads();
  }
#pragma unroll
  for (int p = 0; p < 2; ++p) {
    __syncthreads();
    if (wr == p) {
#pragma unroll
      for (int i = 0; i < 4; ++i)
#pragma unroll
        for (int j = 0; j < 4; ++j) {
          const int n = n0 + wc * 64 + j * 16 + col16;
          const int qn = n & ~1;
          const float freq = exp2f((float)qn * -0.0625f) * 0.15915494309189535f;
          const float cs = colsum[h * NN + n];
#pragma unroll
          for (int r = 0; r < 4; ++r) {
            const int lr = i * 16 + quad * 4 + r;
            const int t = t0 + p * 64 + lr;
            const int lrow = z * TT + t;
            const float muv = mu[lrow], rsv = rs[lrow];
            float ys = fmaxf(rsv * acc[i][j][r] - rsv * muv * cs, 0.f);
            const size_t gi = ((size_t)bh * TT + t) * NN + n;
            float qs = b2f(qr16[gi]);
            float qp = b2f(qr16[gi ^ 1]);
            float phase = (float)t * freq;
            float ph = (phase - floorf(phase)) * 6.283185307179586f;
            float s = __sinf(ph), c = __cosf(ph);
            float xs = (n & 1) ? (qs * c - qp * s) : (qs * c + qp * s);
            float val = ys * xs;
            out2[gi] = val;
            smem[lr * 128 + wc * 64 + j * 16 + col16] = f2b(val);
          }
        }
    }
    __syncthreads();
    copy_out64(smem, xy16 + ((size_t)bh * TT + t0 + p * 64) * NN + n0, NN, tid);
  }
}

// ---------------------------------------------------------------------------
// K5: ymlp = flat(XY16) @ DECT^T.  M=4096, N=768, K=3072.
// A row m=(b,t), k=h*256+n gathered from XY16's (b,h,t,n) layout.
// ---------------------------------------------------------------------------
__global__ __launch_bounds__(256) void k5_mlp(
    const u16* __restrict__ xy16, const u16* __restrict__ dect,
    float* __restrict__ ymlp) {
  const int m0 = blockIdx.x * 128, d0 = blockIdx.y * 128;
  GEMM_PROLOGUE();
  for (int k0 = 0; k0 < NHH * NN; k0 += 32) {
    {  // gather-stage A
      const int l = tid & 63;
      const int hh = k0 >> 8, kk = (k0 & 255) + ((l & 3) << 3);
#pragma unroll
      for (int q = 0; q < 2; ++q) {
        const int row0 = w * 32 + q * 16;
        const int m = m0 + row0 + (l >> 2);
        const int b = m >> 11, t = m & (TT - 1);
        async16(xy16 + ((size_t)(b * NHH + hh) * TT + t) * NN + kk,
                As + row0 * 32);
      }
    }
    stage128x32(dect + (size_t)d0 * (NHH * NN) + k0, NHH * NN, Bs, tid);
    __syncthreads();
    mfma_step(As, Bs, wr, wc, lane, acc);
    __syncthreads();
  }
#pragma unroll
  for (int i = 0; i < 4; ++i)
#pragma unroll
    for (int j = 0; j < 4; ++j) {
      const int d = d0 + wc * 64 + j * 16 + col16;
#pragma unroll
      for (int r = 0; r < 4; ++r) {
        const int m = m0 + wr * 64 + i * 16 + quad * 4 + r;
        ymlp[(size_t)m * DD + d] = acc[i][j][r];
      }
    }
}

// ---------------------------------------------------------------------------
// K6: y = ln(ymlp)*sqrt(0.1/(ra+1e-6))*scale; out1 = ln(x+y). Block per row.
// ---------------------------------------------------------------------------
__global__ __launch_bounds__(256) void k6_final(
    const float* __restrict__ ymlp, const float* __restrict__ x,
    const float* __restrict__ scale, const float* __restrict__ ra,
    float* __restrict__ out1) {
  const int row = blockIdx.x;
  const int tid = threadIdx.x;
  const int wid = tid >> 6, lane = tid & 63;
  __shared__ float red[8];
  float v[3];
  float sum = 0.f, sq = 0.f;
#pragma unroll
  for (int j = 0; j < 3; ++j) {
    v[j] = ymlp[(size_t)row * DD + tid + j * 256];
    sum += v[j]; sq += v[j] * v[j];
  }
#pragma unroll
  for (int off = 32; off; off >>= 1) { sum += __shfl_xor(sum, off); sq += __shfl_xor(sq, off); }
  if (lane == 0) { red[wid] = sum; red[4 + wid] = sq; }
  __syncthreads();
  sum = red[0] + red[1] + red[2] + red[3];
  sq = red[4] + red[5] + red[6] + red[7];
  const float m1 = sum * (1.f / 768.f);
  const float r1 = rsqrtf(sq * (1.f / 768.f) - m1 * m1 + 1e-5f);
  float z[3];
  float sum2 = 0.f, sq2 = 0.f;
#pragma unroll
  for (int j = 0; j < 3; ++j) {
    const int d = tid + j * 256;
    float y = (v[j] - m1) * r1 * sqrtf(0.1f / (ra[d] + 1e-6f)) * scale[d];
    z[j] = x[(size_t)row * DD + d] + y;
    sum2 += z[j]; sq2 += z[j] * z[j];
  }
  __syncthreads();
#pragma unroll
  for (int off = 32; off; off >>= 1) { sum2 += __shfl_xor(sum2, off); sq2 += __shfl_xor(sq2, off); }
  if (lane == 0) { red[wid] = sum2; red[4 + wid] = sq2; }
  __syncthreads();
  sum2 = red[0] + red[1] + red[2] + red[3];
  sq2 = red[4] + red[5] + red[6] + red[7];
  const float m2 = sum2 * (1.f / 768.f);
  const float r2 = rsqrtf(sq2 * (1.f / 768.f) - m2 * m2 + 1e-5f);
#pragma unroll
  for (int j = 0; j < 3; ++j)
    out1[(size_t)row * DD + tid + j * 256] = (z[j] - m2) * r2;
}

// ---------------------------------------------------------------------------
extern "C" void kernel_launch(void* const* d_in, const int* in_sizes, int n_in,
                              void* d_out, int out_size, void* d_ws, size_t ws_size,
                              hipStream_t stream) {
  const float* x = (const float*)d_in[0];
  const float* enc = (const float*)d_in[1];
  const float* encv = (const float*)d_in[2];
  const float* dec = (const float*)d_in[3];
  const float* scale = (const float*)d_in[4];
  const float* ra = (const float*)d_in[5];
  float* out1 = (float*)d_out;
  float* out2 = out1 + (size_t)BB * TT * DD;

  // Fixed buffers in ws (all sizes multiples of 16 B):
  unsigned char* p = (unsigned char*)d_ws;
  u16* X16 = (u16*)p;   p += (size_t)BB * TT * DD * 2;        // [m][d]
  u16* XT16 = (u16*)p;  p += (size_t)BB * DD * TT * 2;        // [b][d][t]
  u16* ENCT = (u16*)p;  p += (size_t)NHH * NN * DD * 2;       // [h][n][d]
  u16* ENCVT = (u16*)p; p += (size_t)NHH * NN * DD * 2;       // [h][n][d]
  u16* DECT = (u16*)p;  p += (size_t)DD * NHH * NN * 2;       // [d][c]
  u16* QR16 = (u16*)p;  p += (size_t)BB * NHH * TT * NN * 2;  // [b][h][t][n]
  u16* XY16 = (u16*)p;  p += (size_t)BB * NHH * TT * NN * 2;  // [b][h][t][n]
  float* COLSUM = (float*)p; p += (size_t)NHH * NN * 4;
  float* ymlp = (float*)p;   p += (size_t)BB * TT * DD * 4;
  // Per-slice pool: S16 (bf16) + ykv16 (bf16) + mu/rs (fp32)
  const size_t SLICE_B = (size_t)TT * TT * 2 + (size_t)TT * DD * 2 + (size_t)TT * 8;
  size_t rem = ws_size - (size_t)(p - (unsigned char*)d_ws);
  int G = (int)(rem / SLICE_B);
  if (G < 1) G = 1;
  if (G > BB * NHH) G = BB * NHH;
  u16* S16 = (u16*)p;
  u16* YKV16 = (u16*)(p + (size_t)G * TT * TT * 2);
  float* MU = (float*)((unsigned char*)YKV16 + (size_t)G * TT * DD * 2);
  float* RS = MU + (size_t)G * TT;

  // One-time conversions / transposes
  cvt_bf16<<<dim3((BB * TT * DD) / 1024), 256, 0, stream>>>(x, X16, (size_t)BB * TT * DD / 4);
  tcvt_bf16<<<dim3(DD / 32, TT / 32, BB), 256, 0, stream>>>(
      x, XT16, TT, DD, (size_t)TT * DD, (size_t)DD * TT);
  tcvt_bf16<<<dim3(NN / 32, DD / 32, NHH), 256, 0, stream>>>(
      enc, ENCT, DD, NN, (size_t)DD * NN, (size_t)NN * DD);
  tcvt_bf16<<<dim3(NN / 32, DD / 32, NHH), 256, 0, stream>>>(
      encv, ENCVT, DD, NN, (size_t)DD * NN, (size_t)NN * DD);
  tcvt_bf16<<<dim3(DD / 32, (NHH * NN) / 32, 1), 256, 0, stream>>>(
      dec, DECT, NHH * NN, DD, 0, 0);
  k_colsum<<<dim3(NHH * NN / 4), 256, 0, stream>>>(ENCVT, COLSUM);

  k1_encode<<<dim3(BB * TT / 128, NN / 128, NHH), 256, 0, stream>>>(X16, ENCT, QR16);

  for (int bh0 = 0; bh0 < BB * NHH; bh0 += G) {
    const int g = imin(G, BB * NHH - bh0);
    k2a_scores<<<dim3(136, g), 256, 0, stream>>>(QR16, S16, bh0);
    k2b_ykv<<<dim3(DD / 128, TT / 128, g), 256, 0, stream>>>(S16, XT16, YKV16, bh0);
    k3_stats<<<dim3(g * TT / 4), 256, 0, stream>>>(YKV16, MU, RS);
    k4_xy<<<dim3(TT / 128, NN / 128, g), 256, 0, stream>>>(
        YKV16, ENCVT, QR16, MU, RS, COLSUM, out2, XY16, bh0);
  }
  k5_mlp<<<dim3(BB * TT / 128, DD / 128), 256, 0, stream>>>(XY16, DECT, ymlp);
  k6_final<<<dim3(BB * TT), 256, 0, stream>>>(ymlp, x, scale, ra, out1);
}